// Round 12
// baseline (369.007 us; speedup 1.0000x reference)
//
#include <hip/hip_runtime.h>
#include <math.h>

#define D 128
#define NSPLIT 4

typedef __bf16 v8bf __attribute__((ext_vector_type(8)));
typedef __bf16 v4bf __attribute__((ext_vector_type(4)));
typedef float v4f __attribute__((ext_vector_type(4)));

__device__ inline v8bf load_cvt8(const float* __restrict__ p) {
  const float4* p4 = (const float4*)p;
  float4 a = p4[0], b = p4[1];
  v8bf r;
  r[0] = (__bf16)a.x; r[1] = (__bf16)a.y; r[2] = (__bf16)a.z; r[3] = (__bf16)a.w;
  r[4] = (__bf16)b.x; r[5] = (__bf16)b.y; r[6] = (__bf16)b.z; r[7] = (__bf16)b.w;
  return r;
}

// async global->LDS, 16 B per lane. Dest must be wave-uniform base (HW adds lane*16).
__device__ inline void async_copy16(const void* gsrc, void* ldst) {
  __builtin_amdgcn_global_load_lds(
      (const __attribute__((address_space(1))) void*)gsrc,
      (__attribute__((address_space(3))) void*)ldst, 16, 0, 0);
}

// One fused kernel: blockIdx.y selects {0: q-proj, 1: k-proj, 2: v-proj-T}.
// (unchanged — proj is not the lever; non-attn time is harness-constant)
__global__ __launch_bounds__(256) void proj_all(
    const float* __restrict__ Q, const float* __restrict__ K,
    const float* __restrict__ V,
    const float* __restrict__ Wq, const float* __restrict__ bq,
    const float* __restrict__ Wk, const float* __restrict__ bk,
    const float* __restrict__ Wv, const float* __restrict__ bv,
    __bf16* __restrict__ qbf, __bf16* __restrict__ kbf,
    __bf16* __restrict__ vtbf, int Nk, float alpha)
{
  __shared__ __align__(16) __bf16 w_lds[128][136];

  const float* W    = (blockIdx.y == 0) ? Wq : (blockIdx.y == 1) ? Wk : Wv;
  const float* bias = (blockIdx.y == 0) ? bq : (blockIdx.y == 1) ? bk : bv;

  {
    const int tid = threadIdx.x;
    const int r = tid >> 1;
    const int h = (tid & 1) * 64;
    #pragma unroll
    for (int i = 0; i < 8; ++i) {
      v8bf v = load_cvt8(W + r * D + h + i * 8);
      *(v8bf*)&w_lds[r][h + i * 8] = v;
    }
  }
  __syncthreads();

  const int w = threadIdx.x >> 6, l = threadIdx.x & 63;
  const int l16 = l & 15, l4 = l >> 4;

  if (blockIdx.y < 2) {
    const float* X = (blockIdx.y == 0) ? Q : K;
    __bf16* Y      = (blockIdx.y == 0) ? qbf : kbf;
    const float a  = (blockIdx.y == 0) ? alpha : 1.0f;
    const size_t rbase = (size_t)blockIdx.x * 64 + w * 16;

    v4f acc[8];
    #pragma unroll
    for (int ct = 0; ct < 8; ++ct) acc[ct] = (v4f){0.f, 0.f, 0.f, 0.f};

    #pragma unroll
    for (int kk = 0; kk < 4; ++kk) {
      v8bf xv = load_cvt8(X + (rbase + l16) * D + kk * 32 + l4 * 8);
      #pragma unroll
      for (int ct = 0; ct < 8; ++ct) {
        v8bf wv = *(const v8bf*)&w_lds[ct * 16 + l16][kk * 32 + l4 * 8];
        acc[ct] = __builtin_amdgcn_mfma_f32_16x16x32_bf16(wv, xv, acc[ct], 0, 0, 0);
      }
    }
    const size_t qrow = rbase + l16;
    #pragma unroll
    for (int ct = 0; ct < 8; ++ct) {
      const int e0 = ct * 16 + l4 * 4;
      float4 b4 = *(const float4*)(bias + e0);
      v4bf o;
      o[0] = (__bf16)((acc[ct][0] + b4.x) * a);
      o[1] = (__bf16)((acc[ct][1] + b4.y) * a);
      o[2] = (__bf16)((acc[ct][2] + b4.z) * a);
      o[3] = (__bf16)((acc[ct][3] + b4.w) * a);
      *(v4bf*)(Y + qrow * D + e0) = o;
    }
  } else {
    const int bx = blockIdx.x;
    const int b = bx >> 6;
    const float* Xb = V + (size_t)b * Nk * D;
    __bf16* VTb = vtbf + (size_t)b * D * Nk;
    const int ebase = w * 32;
    const int nbase = (bx & 63) * 64;

    v4f acc[4][2];  // [nt][et]
    #pragma unroll
    for (int nt = 0; nt < 4; ++nt)
      #pragma unroll
      for (int et = 0; et < 2; ++et) acc[nt][et] = (v4f){0.f, 0.f, 0.f, 0.f};

    #pragma unroll
    for (int kk = 0; kk < 4; ++kk) {
      v8bf wv0 = *(const v8bf*)&w_lds[ebase + l16][kk * 32 + l4 * 8];
      v8bf wv1 = *(const v8bf*)&w_lds[ebase + 16 + l16][kk * 32 + l4 * 8];
      #pragma unroll
      for (int nt = 0; nt < 4; ++nt) {
        v8bf xv = load_cvt8(Xb + (size_t)(nbase + nt * 16 + l16) * D + kk * 32 + l4 * 8);
        acc[nt][0] = __builtin_amdgcn_mfma_f32_16x16x32_bf16(xv, wv0, acc[nt][0], 0, 0, 0);
        acc[nt][1] = __builtin_amdgcn_mfma_f32_16x16x32_bf16(xv, wv1, acc[nt][1], 0, 0, 0);
      }
    }
    #pragma unroll
    for (int et = 0; et < 2; ++et) {
      const int e = ebase + et * 16 + l16;
      const float bv2 = bias[e];
      __bf16* dst = VTb + (size_t)e * Nk + nbase;
      #pragma unroll
      for (int nt = 0; nt < 4; ++nt) {
        v4bf o;
        o[0] = (__bf16)(acc[nt][et][0] + bv2);
        o[1] = (__bf16)(acc[nt][et][1] + bv2);
        o[2] = (__bf16)(acc[nt][et][2] + bv2);
        o[3] = (__bf16)(acc[nt][et][3] + bv2);
        *(v4bf*)(dst + nt * 16 + l4 * 4) = o;
      }
    }
  }
}

// Flash attention. 4 waves x 32 q-rows (2 subtiles/wave for K/V-frag reuse).
// SINGLE-buffered K/V (two barriers/tile): LDS = 16K + 16K + 16K = 48 KB ->
// 3 blocks/CU = 12 waves/CU (r10 was 80 KB -> 2 blocks, 8 waves; dbuf gain was
// only ~5% while occupancy was the binder — inter-block overlap hides staging).
// launch_bounds arg2 = blocks/CU on this hipcc (r5: (512,4)->cap64 spill).
__global__ __launch_bounds__(256, 3) void attn_fwd(
    const __bf16* __restrict__ Qb, const __bf16* __restrict__ Kb,
    const __bf16* __restrict__ VTb, float* __restrict__ Out,
    float2* __restrict__ ml, int Nq, int Nk, int NS, int B)
{
  // bijective XCD-chunked swizzle (nwg % 8 == 0)
  const int nwg = gridDim.x;
  int id = blockIdx.x;
  id = (id & 7) * (nwg >> 3) + (id >> 3);
  const int nx = Nq >> 7;            // blocks along q (128 rows each)
  const int x = id % nx;
  const int s = (id / nx) % NS;
  const int b = id / (nx * NS);

  const int w = threadIdx.x >> 6, l = threadIdx.x & 63;
  const int l16 = l & 15, l4 = l >> 4;
  const int qbase = x * 128 + w * 32;     // 32 q-rows per wave
  const int chunk = Nk / NS;
  const int kvbeg = s * chunk;
  const int ntiles = chunk >> 6;

  const __bf16* q = Qb + ((size_t)b * Nq + qbase) * D;
  const char* kg0 = (const char*)(Kb + (size_t)b * Nk * D);
  const char* vg0 = (const char*)(VTb + (size_t)b * D * Nk);

  __shared__ __align__(16) char k_lds[16384];
  __shared__ __align__(16) char v_lds[16384];
  __shared__ __align__(16) char p_lds[4 * 4096];
  char* my_p = p_lds + w * 4096;

  const int NkB = Nk * 2;

  // Q fragments for both subtiles (qs = 0,1)
  v8bf aq[2][4];
  #pragma unroll
  for (int qs = 0; qs < 2; ++qs)
    #pragma unroll
    for (int kk = 0; kk < 4; ++kk)
      aq[qs][kk] = *(const v8bf*)(q + (qs * 16 + l16) * D + kk * 32 + l4 * 8);

  v4f accO[2][8];
  #pragma unroll
  for (int qs = 0; qs < 2; ++qs)
    #pragma unroll
    for (int ct = 0; ct < 8; ++ct) accO[qs][ct] = (v4f){0.f, 0.f, 0.f, 0.f};
  float m[2][4], lsum[2][4];
  #pragma unroll
  for (int qs = 0; qs < 2; ++qs)
    #pragma unroll
    for (int r = 0; r < 4; ++r) { m[qs][r] = -1e30f; lsum[qs][r] = 0.f; }

  // ---- staging: 4 waves x 4 sweeps each for K and V (single buffer) ----
  auto stage = [&](int kv0) {
    const char* kg = kg0 + (size_t)kv0 * (D * 2);
    #pragma unroll
    for (int sweep = 0; sweep < 4; ++sweep) {
      const int flat = sweep * 4096 + w * 1024 + l * 16;
      const int row = flat >> 8;
      const int c = flat & 255;
      async_copy16(kg + ((row << 8) | (c ^ ((row & 7) << 4))),
                   &k_lds[sweep * 4096 + w * 1024]);
    }
    const char* vg = vg0 + (size_t)kv0 * 2;
    #pragma unroll
    for (int sweep = 0; sweep < 4; ++sweep) {
      const int flat = sweep * 4096 + w * 1024 + l * 16;
      const int row = flat >> 7;
      const int c = flat & 127;
      async_copy16(vg + (size_t)row * NkB + (c ^ ((row & 7) << 4)),
                   &v_lds[sweep * 4096 + w * 1024]);
    }
  };

  stage(kvbeg);
  __syncthreads();  // vmcnt(0) drain: first tile visible

  for (int t = 0; t < ntiles; ++t) {
    // ---- S = q @ k^T (32 x 64): K-frag read once, used by both subtiles ----
    v4f sc4[2][4];
    #pragma unroll
    for (int qs = 0; qs < 2; ++qs)
      #pragma unroll
      for (int ct = 0; ct < 4; ++ct) sc4[qs][ct] = (v4f){0.f, 0.f, 0.f, 0.f};
    #pragma unroll
    for (int ct = 0; ct < 4; ++ct) {
      const int krow = ct * 16 + l16;
      const int sw = (krow & 7) << 4;
      #pragma unroll
      for (int kk = 0; kk < 4; ++kk) {
        const int cb = kk * 64 + l4 * 16;
        v8bf bk = *(const v8bf*)(&k_lds[krow * 256 + (cb ^ sw)]);
        sc4[0][ct] = __builtin_amdgcn_mfma_f32_16x16x32_bf16(aq[0][kk], bk, sc4[0][ct], 0, 0, 0);
        sc4[1][ct] = __builtin_amdgcn_mfma_f32_16x16x32_bf16(aq[1][kk], bk, sc4[1][ct], 0, 0, 0);
      }
    }

    // ---- deferred-max online softmax (log2 domain, THR = 8), per subtile ----
    #pragma unroll
    for (int qs = 0; qs < 2; ++qs) {
      float lmax[4];
      float g = -1e30f;
      #pragma unroll
      for (int r = 0; r < 4; ++r) {
        lmax[r] = fmaxf(fmaxf(sc4[qs][0][r], sc4[qs][1][r]),
                        fmaxf(sc4[qs][2][r], sc4[qs][3][r]));
        g = fmaxf(g, lmax[r] - m[qs][r]);
      }
      if (__all(g <= 8.0f)) {
        #pragma unroll
        for (int r = 0; r < 4; ++r) {
          float rs = 0.f;
          #pragma unroll
          for (int ct = 0; ct < 4; ++ct) {
            float p = exp2f(sc4[qs][ct][r] - m[qs][r]);
            sc4[qs][ct][r] = p;
            rs += p;
          }
          lsum[qs][r] += rs;
        }
      } else {
        float scale[4];
        #pragma unroll
        for (int r = 0; r < 4; ++r) {
          float mx = lmax[r];
          #pragma unroll
          for (int off = 8; off; off >>= 1) mx = fmaxf(mx, __shfl_xor(mx, off, 64));
          float mn = fmaxf(m[qs][r], mx);
          scale[r] = exp2f(m[qs][r] - mn);
          m[qs][r] = mn;
          float rs = 0.f;
          #pragma unroll
          for (int ct = 0; ct < 4; ++ct) {
            float p = exp2f(sc4[qs][ct][r] - mn);
            sc4[qs][ct][r] = p;
            rs += p;
          }
          lsum[qs][r] = lsum[qs][r] * scale[r] + rs;
        }
        #pragma unroll
        for (int ct = 0; ct < 8; ++ct)
          #pragma unroll
          for (int r = 0; r < 4; ++r) accO[qs][ct][r] *= scale[r];
      }

      // D-layout -> A-layout transpose of P (per-wave, swizzled LDS)
      #pragma unroll
      for (int ct = 0; ct < 4; ++ct)
        #pragma unroll
        for (int r = 0; r < 4; ++r) {
          const int row = l4 * 4 + r;
          const int byte = qs * 2048 + row * 128 +
                           ((ct * 32 + l16 * 2) ^ ((row & 7) << 4));
          *(__bf16*)(my_p + byte) = (__bf16)sc4[qs][ct][r];
        }
    }

    // ---- O += P @ V: V-frag read once, used by both subtiles ----
    #pragma unroll
    for (int ks = 0; ks < 2; ++ks) {
      const int cbp = ks * 64 + l4 * 16;
      v8bf ap0 = *(const v8bf*)(my_p + l16 * 128 + (cbp ^ ((l16 & 7) << 4)));
      v8bf ap1 = *(const v8bf*)(my_p + 2048 + l16 * 128 + (cbp ^ ((l16 & 7) << 4)));
      #pragma unroll
      for (int ct = 0; ct < 8; ++ct) {
        const int vrow = ct * 16 + l16;
        const int cb = ks * 64 + l4 * 16;
        v8bf bv = *(const v8bf*)(&v_lds[vrow * 128 + (cb ^ ((vrow & 7) << 4))]);
        accO[0][ct] = __builtin_amdgcn_mfma_f32_16x16x32_bf16(ap0, bv, accO[0][ct], 0, 0, 0);
        accO[1][ct] = __builtin_amdgcn_mfma_f32_16x16x32_bf16(ap1, bv, accO[1][ct], 0, 0, 0);
      }
    }

    if (t + 1 < ntiles) {
      __syncthreads();                 // all waves done reading this tile
      stage(kvbeg + (t + 1) * 64);     // overwrite single buffer
      __syncthreads();                 // vmcnt(0) drain: next tile visible
    }
  }

  #pragma unroll
  for (int qs = 0; qs < 2; ++qs)
    #pragma unroll
    for (int r = 0; r < 4; ++r) {
      float t2 = lsum[qs][r];
      #pragma unroll
      for (int off = 8; off; off >>= 1) t2 += __shfl_xor(t2, off, 64);
      lsum[qs][r] = t2;
    }

  float* outp = Out + (((size_t)s * B + b) * Nq + qbase) * D;
  if (NS == 1) {
    #pragma unroll
    for (int qs = 0; qs < 2; ++qs)
      #pragma unroll
      for (int ct = 0; ct < 8; ++ct)
        #pragma unroll
        for (int r = 0; r < 4; ++r)
          outp[(size_t)(qs * 16 + l4 * 4 + r) * D + ct * 16 + l16] =
              accO[qs][ct][r] / lsum[qs][r];
  } else {
    #pragma unroll
    for (int qs = 0; qs < 2; ++qs)
      #pragma unroll
      for (int ct = 0; ct < 8; ++ct)
        #pragma unroll
        for (int r = 0; r < 4; ++r)
          outp[(size_t)(qs * 16 + l4 * 4 + r) * D + ct * 16 + l16] = accO[qs][ct][r];
    if (l16 == 0) {
      #pragma unroll
      for (int qs = 0; qs < 2; ++qs)
        #pragma unroll
        for (int r = 0; r < 4; ++r) {
          size_t row = (size_t)b * Nq + qbase + qs * 16 + l4 * 4 + r;
          ml[(size_t)s * B * Nq + row] = make_float2(m[qs][r], lsum[qs][r]);
        }
    }
  }
}

__global__ __launch_bounds__(256) void attn_combine(
    const float* __restrict__ Opart, const float2* __restrict__ ml,
    float* __restrict__ out, int NS, int rowsTotal)
{
  const int t = threadIdx.x;
  const size_t row = (size_t)blockIdx.x * 2 + (t >> 7);
  const int d = t & 127;

  float mv[NSPLIT], lv[NSPLIT];
  float M = -1e30f;
  #pragma unroll
  for (int s = 0; s < NSPLIT; ++s) {
    float2 x = ml[(size_t)s * rowsTotal + row];
    mv[s] = x.x; lv[s] = x.y;
    M = fmaxf(M, x.x);
  }
  float denom = 0.f, acc = 0.f;
  #pragma unroll
  for (int s = 0; s < NSPLIT; ++s) {
    float wgt = exp2f(mv[s] - M);
    denom += wgt * lv[s];
    acc += wgt * Opart[((size_t)s * rowsTotal + row) * D + d];
  }
  out[row * D + d] = acc / denom;
}

extern "C" void kernel_launch(void* const* d_in, const int* in_sizes, int n_in,
                              void* d_out, int out_size, void* d_ws, size_t ws_size,
                              hipStream_t stream) {
  const float* Q  = (const float*)d_in[0];
  const float* K  = (const float*)d_in[1];
  const float* V  = (const float*)d_in[2];
  const float* Wq = (const float*)d_in[3];
  const float* bq = (const float*)d_in[4];
  const float* Wk = (const float*)d_in[5];
  const float* bk = (const float*)d_in[6];
  const float* Wv = (const float*)d_in[7];
  const float* bv = (const float*)d_in[8];
  float* out = (float*)d_out;

  const int B = 4, Nq = 4096, Nk = 4096;
  const size_t nElems = (size_t)B * Nq * D;
  const size_t bfBytes = nElems * 2;

  char* ws = (char*)d_ws;
  __bf16* qbf  = (__bf16*)(ws);
  __bf16* kbf  = (__bf16*)(ws + bfBytes);
  __bf16* vtbf = (__bf16*)(ws + 2 * bfBytes);
  float*  Opart = (float*)(ws + 3 * bfBytes);
  float2* mlp   = (float2*)(ws + 3 * bfBytes + (size_t)NSPLIT * nElems * 4);

  const size_t needSplit = 3 * bfBytes + (size_t)NSPLIT * nElems * 4 +
                           (size_t)NSPLIT * B * Nq * 8;
  const int NS = (ws_size >= needSplit) ? NSPLIT : 1;

  const float alpha = 1.4426950408889634f / sqrtf((float)D);  // log2(e)/sqrt(D)

  proj_all<<<dim3(B * Nq / 64, 3), 256, 0, stream>>>(
      Q, K, V, Wq, bq, Wk, bk, Wv, bv, qbf, kbf, vtbf, Nk, alpha);

  const int nx = Nq / 128;
  if (NS == 1) {
    attn_fwd<<<dim3(nx * B), 256, 0, stream>>>(
        qbf, kbf, vtbf, out, nullptr, Nq, Nk, 1, B);
  } else {
    attn_fwd<<<dim3(nx * NS * B), 256, 0, stream>>>(
        qbf, kbf, vtbf, Opart, mlp, Nq, Nk, NS, B);
    attn_combine<<<dim3(B * Nq / 2), 256, 0, stream>>>(
        Opart, mlp, out, NS, B * Nq);
  }
}

// Round 13
// 167.776 us; speedup vs baseline: 2.1994x; 2.1994x over previous
//
#include <hip/hip_runtime.h>
#include <math.h>

#define D 128
#define NSPLIT 4

typedef __bf16 v8bf __attribute__((ext_vector_type(8)));
typedef __bf16 v4bf __attribute__((ext_vector_type(4)));
typedef float v4f __attribute__((ext_vector_type(4)));

__device__ inline v8bf load_cvt8(const float* __restrict__ p) {
  const float4* p4 = (const float4*)p;
  float4 a = p4[0], b = p4[1];
  v8bf r;
  r[0] = (__bf16)a.x; r[1] = (__bf16)a.y; r[2] = (__bf16)a.z; r[3] = (__bf16)a.w;
  r[4] = (__bf16)b.x; r[5] = (__bf16)b.y; r[6] = (__bf16)b.z; r[7] = (__bf16)b.w;
  return r;
}

// async global->LDS, 16 B per lane. Dest must be wave-uniform base (HW adds lane*16).
__device__ inline void async_copy16(const void* gsrc, void* ldst) {
  __builtin_amdgcn_global_load_lds(
      (const __attribute__((address_space(1))) void*)gsrc,
      (__attribute__((address_space(3))) void*)ldst, 16, 0, 0);
}

// One fused kernel: blockIdx.y selects {0: q-proj, 1: k-proj, 2: v-proj-T}.
// (unchanged — proj is not the lever; non-attn time is harness-constant)
__global__ __launch_bounds__(256) void proj_all(
    const float* __restrict__ Q, const float* __restrict__ K,
    const float* __restrict__ V,
    const float* __restrict__ Wq, const float* __restrict__ bq,
    const float* __restrict__ Wk, const float* __restrict__ bk,
    const float* __restrict__ Wv, const float* __restrict__ bv,
    __bf16* __restrict__ qbf, __bf16* __restrict__ kbf,
    __bf16* __restrict__ vtbf, int Nk, float alpha)
{
  __shared__ __align__(16) __bf16 w_lds[128][136];

  const float* W    = (blockIdx.y == 0) ? Wq : (blockIdx.y == 1) ? Wk : Wv;
  const float* bias = (blockIdx.y == 0) ? bq : (blockIdx.y == 1) ? bk : bv;

  {
    const int tid = threadIdx.x;
    const int r = tid >> 1;
    const int h = (tid & 1) * 64;
    #pragma unroll
    for (int i = 0; i < 8; ++i) {
      v8bf v = load_cvt8(W + r * D + h + i * 8);
      *(v8bf*)&w_lds[r][h + i * 8] = v;
    }
  }
  __syncthreads();

  const int w = threadIdx.x >> 6, l = threadIdx.x & 63;
  const int l16 = l & 15, l4 = l >> 4;

  if (blockIdx.y < 2) {
    const float* X = (blockIdx.y == 0) ? Q : K;
    __bf16* Y      = (blockIdx.y == 0) ? qbf : kbf;
    const float a  = (blockIdx.y == 0) ? alpha : 1.0f;
    const size_t rbase = (size_t)blockIdx.x * 64 + w * 16;

    v4f acc[8];
    #pragma unroll
    for (int ct = 0; ct < 8; ++ct) acc[ct] = (v4f){0.f, 0.f, 0.f, 0.f};

    #pragma unroll
    for (int kk = 0; kk < 4; ++kk) {
      v8bf xv = load_cvt8(X + (rbase + l16) * D + kk * 32 + l4 * 8);
      #pragma unroll
      for (int ct = 0; ct < 8; ++ct) {
        v8bf wv = *(const v8bf*)&w_lds[ct * 16 + l16][kk * 32 + l4 * 8];
        acc[ct] = __builtin_amdgcn_mfma_f32_16x16x32_bf16(wv, xv, acc[ct], 0, 0, 0);
      }
    }
    const size_t qrow = rbase + l16;
    #pragma unroll
    for (int ct = 0; ct < 8; ++ct) {
      const int e0 = ct * 16 + l4 * 4;
      float4 b4 = *(const float4*)(bias + e0);
      v4bf o;
      o[0] = (__bf16)((acc[ct][0] + b4.x) * a);
      o[1] = (__bf16)((acc[ct][1] + b4.y) * a);
      o[2] = (__bf16)((acc[ct][2] + b4.z) * a);
      o[3] = (__bf16)((acc[ct][3] + b4.w) * a);
      *(v4bf*)(Y + qrow * D + e0) = o;
    }
  } else {
    const int bx = blockIdx.x;
    const int b = bx >> 6;
    const float* Xb = V + (size_t)b * Nk * D;
    __bf16* VTb = vtbf + (size_t)b * D * Nk;
    const int ebase = w * 32;
    const int nbase = (bx & 63) * 64;

    v4f acc[4][2];  // [nt][et]
    #pragma unroll
    for (int nt = 0; nt < 4; ++nt)
      #pragma unroll
      for (int et = 0; et < 2; ++et) acc[nt][et] = (v4f){0.f, 0.f, 0.f, 0.f};

    #pragma unroll
    for (int kk = 0; kk < 4; ++kk) {
      v8bf wv0 = *(const v8bf*)&w_lds[ebase + l16][kk * 32 + l4 * 8];
      v8bf wv1 = *(const v8bf*)&w_lds[ebase + 16 + l16][kk * 32 + l4 * 8];
      #pragma unroll
      for (int nt = 0; nt < 4; ++nt) {
        v8bf xv = load_cvt8(Xb + (size_t)(nbase + nt * 16 + l16) * D + kk * 32 + l4 * 8);
        acc[nt][0] = __builtin_amdgcn_mfma_f32_16x16x32_bf16(xv, wv0, acc[nt][0], 0, 0, 0);
        acc[nt][1] = __builtin_amdgcn_mfma_f32_16x16x32_bf16(xv, wv1, acc[nt][1], 0, 0, 0);
      }
    }
    #pragma unroll
    for (int et = 0; et < 2; ++et) {
      const int e = ebase + et * 16 + l16;
      const float bv2 = bias[e];
      __bf16* dst = VTb + (size_t)e * Nk + nbase;
      #pragma unroll
      for (int nt = 0; nt < 4; ++nt) {
        v4bf o;
        o[0] = (__bf16)(acc[nt][et][0] + bv2);
        o[1] = (__bf16)(acc[nt][et][1] + bv2);
        o[2] = (__bf16)(acc[nt][et][2] + bv2);
        o[3] = (__bf16)(acc[nt][et][3] + bv2);
        *(v4bf*)(dst + nt * 16 + l4 * 4) = o;
      }
    }
  }
}

// Flash attention. 4 waves x 32 q-rows (2 subtiles/wave for K/V-frag reuse).
// SINGLE-buffered K/V: LDS = 48 KB -> 3 blocks/CU (12 waves/CU).
// EMPIRICAL launch_bounds model on this hipcc: VGPR cap = 256/arg2
//   ((512,4)->64 spill r5; (512,2)->128; (256,2)->128; (256,3)->85 spill r12).
// arg2=2 -> cap 128: fits (r10's bigger variant used exactly 128), and 128
// VGPR allows 4 waves/SIMD so LDS (3 blocks) is the occupancy binder.
__global__ __launch_bounds__(256, 2) void attn_fwd(
    const __bf16* __restrict__ Qb, const __bf16* __restrict__ Kb,
    const __bf16* __restrict__ VTb, float* __restrict__ Out,
    float2* __restrict__ ml, int Nq, int Nk, int NS, int B)
{
  // bijective XCD-chunked swizzle (nwg % 8 == 0)
  const int nwg = gridDim.x;
  int id = blockIdx.x;
  id = (id & 7) * (nwg >> 3) + (id >> 3);
  const int nx = Nq >> 7;            // blocks along q (128 rows each)
  const int x = id % nx;
  const int s = (id / nx) % NS;
  const int b = id / (nx * NS);

  const int w = threadIdx.x >> 6, l = threadIdx.x & 63;
  const int l16 = l & 15, l4 = l >> 4;
  const int qbase = x * 128 + w * 32;     // 32 q-rows per wave
  const int chunk = Nk / NS;
  const int kvbeg = s * chunk;
  const int ntiles = chunk >> 6;

  const __bf16* q = Qb + ((size_t)b * Nq + qbase) * D;
  const char* kg0 = (const char*)(Kb + (size_t)b * Nk * D);
  const char* vg0 = (const char*)(VTb + (size_t)b * D * Nk);

  __shared__ __align__(16) char k_lds[16384];
  __shared__ __align__(16) char v_lds[16384];
  __shared__ __align__(16) char p_lds[4 * 4096];
  char* my_p = p_lds + w * 4096;

  const int NkB = Nk * 2;

  // Q fragments for both subtiles (qs = 0,1)
  v8bf aq[2][4];
  #pragma unroll
  for (int qs = 0; qs < 2; ++qs)
    #pragma unroll
    for (int kk = 0; kk < 4; ++kk)
      aq[qs][kk] = *(const v8bf*)(q + (qs * 16 + l16) * D + kk * 32 + l4 * 8);

  v4f accO[2][8];
  #pragma unroll
  for (int qs = 0; qs < 2; ++qs)
    #pragma unroll
    for (int ct = 0; ct < 8; ++ct) accO[qs][ct] = (v4f){0.f, 0.f, 0.f, 0.f};
  float m[2][4], lsum[2][4];
  #pragma unroll
  for (int qs = 0; qs < 2; ++qs)
    #pragma unroll
    for (int r = 0; r < 4; ++r) { m[qs][r] = -1e30f; lsum[qs][r] = 0.f; }

  // ---- staging: 4 waves x 4 sweeps each for K and V (single buffer) ----
  auto stage = [&](int kv0) {
    const char* kg = kg0 + (size_t)kv0 * (D * 2);
    #pragma unroll
    for (int sweep = 0; sweep < 4; ++sweep) {
      const int flat = sweep * 4096 + w * 1024 + l * 16;
      const int row = flat >> 8;
      const int c = flat & 255;
      async_copy16(kg + ((row << 8) | (c ^ ((row & 7) << 4))),
                   &k_lds[sweep * 4096 + w * 1024]);
    }
    const char* vg = vg0 + (size_t)kv0 * 2;
    #pragma unroll
    for (int sweep = 0; sweep < 4; ++sweep) {
      const int flat = sweep * 4096 + w * 1024 + l * 16;
      const int row = flat >> 7;
      const int c = flat & 127;
      async_copy16(vg + (size_t)row * NkB + (c ^ ((row & 7) << 4)),
                   &v_lds[sweep * 4096 + w * 1024]);
    }
  };

  stage(kvbeg);
  __syncthreads();  // vmcnt(0) drain: first tile visible

  for (int t = 0; t < ntiles; ++t) {
    // ---- S = q @ k^T (32 x 64): K-frag read once, used by both subtiles ----
    v4f sc4[2][4];
    #pragma unroll
    for (int qs = 0; qs < 2; ++qs)
      #pragma unroll
      for (int ct = 0; ct < 4; ++ct) sc4[qs][ct] = (v4f){0.f, 0.f, 0.f, 0.f};
    #pragma unroll
    for (int ct = 0; ct < 4; ++ct) {
      const int krow = ct * 16 + l16;
      const int sw = (krow & 7) << 4;
      #pragma unroll
      for (int kk = 0; kk < 4; ++kk) {
        const int cb = kk * 64 + l4 * 16;
        v8bf bk = *(const v8bf*)(&k_lds[krow * 256 + (cb ^ sw)]);
        sc4[0][ct] = __builtin_amdgcn_mfma_f32_16x16x32_bf16(aq[0][kk], bk, sc4[0][ct], 0, 0, 0);
        sc4[1][ct] = __builtin_amdgcn_mfma_f32_16x16x32_bf16(aq[1][kk], bk, sc4[1][ct], 0, 0, 0);
      }
    }

    // ---- deferred-max online softmax (log2 domain, THR = 8), per subtile ----
    #pragma unroll
    for (int qs = 0; qs < 2; ++qs) {
      float lmax[4];
      float g = -1e30f;
      #pragma unroll
      for (int r = 0; r < 4; ++r) {
        lmax[r] = fmaxf(fmaxf(sc4[qs][0][r], sc4[qs][1][r]),
                        fmaxf(sc4[qs][2][r], sc4[qs][3][r]));
        g = fmaxf(g, lmax[r] - m[qs][r]);
      }
      if (__all(g <= 8.0f)) {
        #pragma unroll
        for (int r = 0; r < 4; ++r) {
          float rs = 0.f;
          #pragma unroll
          for (int ct = 0; ct < 4; ++ct) {
            float p = exp2f(sc4[qs][ct][r] - m[qs][r]);
            sc4[qs][ct][r] = p;
            rs += p;
          }
          lsum[qs][r] += rs;
        }
      } else {
        float scale[4];
        #pragma unroll
        for (int r = 0; r < 4; ++r) {
          float mx = lmax[r];
          #pragma unroll
          for (int off = 8; off; off >>= 1) mx = fmaxf(mx, __shfl_xor(mx, off, 64));
          float mn = fmaxf(m[qs][r], mx);
          scale[r] = exp2f(m[qs][r] - mn);
          m[qs][r] = mn;
          float rs = 0.f;
          #pragma unroll
          for (int ct = 0; ct < 4; ++ct) {
            float p = exp2f(sc4[qs][ct][r] - mn);
            sc4[qs][ct][r] = p;
            rs += p;
          }
          lsum[qs][r] = lsum[qs][r] * scale[r] + rs;
        }
        #pragma unroll
        for (int ct = 0; ct < 8; ++ct)
          #pragma unroll
          for (int r = 0; r < 4; ++r) accO[qs][ct][r] *= scale[r];
      }

      // D-layout -> A-layout transpose of P (per-wave, swizzled LDS)
      #pragma unroll
      for (int ct = 0; ct < 4; ++ct)
        #pragma unroll
        for (int r = 0; r < 4; ++r) {
          const int row = l4 * 4 + r;
          const int byte = qs * 2048 + row * 128 +
                           ((ct * 32 + l16 * 2) ^ ((row & 7) << 4));
          *(__bf16*)(my_p + byte) = (__bf16)sc4[qs][ct][r];
        }
    }

    // ---- O += P @ V: V-frag read once, used by both subtiles ----
    #pragma unroll
    for (int ks = 0; ks < 2; ++ks) {
      const int cbp = ks * 64 + l4 * 16;
      v8bf ap0 = *(const v8bf*)(my_p + l16 * 128 + (cbp ^ ((l16 & 7) << 4)));
      v8bf ap1 = *(const v8bf*)(my_p + 2048 + l16 * 128 + (cbp ^ ((l16 & 7) << 4)));
      #pragma unroll
      for (int ct = 0; ct < 8; ++ct) {
        const int vrow = ct * 16 + l16;
        const int cb = ks * 64 + l4 * 16;
        v8bf bv = *(const v8bf*)(&v_lds[vrow * 128 + (cb ^ ((vrow & 7) << 4))]);
        accO[0][ct] = __builtin_amdgcn_mfma_f32_16x16x32_bf16(ap0, bv, accO[0][ct], 0, 0, 0);
        accO[1][ct] = __builtin_amdgcn_mfma_f32_16x16x32_bf16(ap1, bv, accO[1][ct], 0, 0, 0);
      }
    }

    if (t + 1 < ntiles) {
      __syncthreads();                 // all waves done reading this tile
      stage(kvbeg + (t + 1) * 64);     // overwrite single buffer
      __syncthreads();                 // vmcnt(0) drain: next tile visible
    }
  }

  #pragma unroll
  for (int qs = 0; qs < 2; ++qs)
    #pragma unroll
    for (int r = 0; r < 4; ++r) {
      float t2 = lsum[qs][r];
      #pragma unroll
      for (int off = 8; off; off >>= 1) t2 += __shfl_xor(t2, off, 64);
      lsum[qs][r] = t2;
    }

  float* outp = Out + (((size_t)s * B + b) * Nq + qbase) * D;
  if (NS == 1) {
    #pragma unroll
    for (int qs = 0; qs < 2; ++qs)
      #pragma unroll
      for (int ct = 0; ct < 8; ++ct)
        #pragma unroll
        for (int r = 0; r < 4; ++r)
          outp[(size_t)(qs * 16 + l4 * 4 + r) * D + ct * 16 + l16] =
              accO[qs][ct][r] / lsum[qs][r];
  } else {
    #pragma unroll
    for (int qs = 0; qs < 2; ++qs)
      #pragma unroll
      for (int ct = 0; ct < 8; ++ct)
        #pragma unroll
        for (int r = 0; r < 4; ++r)
          outp[(size_t)(qs * 16 + l4 * 4 + r) * D + ct * 16 + l16] = accO[qs][ct][r];
    if (l16 == 0) {
      #pragma unroll
      for (int qs = 0; qs < 2; ++qs)
        #pragma unroll
        for (int r = 0; r < 4; ++r) {
          size_t row = (size_t)b * Nq + qbase + qs * 16 + l4 * 4 + r;
          ml[(size_t)s * B * Nq + row] = make_float2(m[qs][r], lsum[qs][r]);
        }
    }
  }
}

__global__ __launch_bounds__(256) void attn_combine(
    const float* __restrict__ Opart, const float2* __restrict__ ml,
    float* __restrict__ out, int NS, int rowsTotal)
{
  const int t = threadIdx.x;
  const size_t row = (size_t)blockIdx.x * 2 + (t >> 7);
  const int d = t & 127;

  float mv[NSPLIT], lv[NSPLIT];
  float M = -1e30f;
  #pragma unroll
  for (int s = 0; s < NSPLIT; ++s) {
    float2 x = ml[(size_t)s * rowsTotal + row];
    mv[s] = x.x; lv[s] = x.y;
    M = fmaxf(M, x.x);
  }
  float denom = 0.f, acc = 0.f;
  #pragma unroll
  for (int s = 0; s < NSPLIT; ++s) {
    float wgt = exp2f(mv[s] - M);
    denom += wgt * lv[s];
    acc += wgt * Opart[((size_t)s * rowsTotal + row) * D + d];
  }
  out[row * D + d] = acc / denom;
}

extern "C" void kernel_launch(void* const* d_in, const int* in_sizes, int n_in,
                              void* d_out, int out_size, void* d_ws, size_t ws_size,
                              hipStream_t stream) {
  const float* Q  = (const float*)d_in[0];
  const float* K  = (const float*)d_in[1];
  const float* V  = (const float*)d_in[2];
  const float* Wq = (const float*)d_in[3];
  const float* bq = (const float*)d_in[4];
  const float* Wk = (const float*)d_in[5];
  const float* bk = (const float*)d_in[6];
  const float* Wv = (const float*)d_in[7];
  const float* bv = (const float*)d_in[8];
  float* out = (float*)d_out;

  const int B = 4, Nq = 4096, Nk = 4096;
  const size_t nElems = (size_t)B * Nq * D;
  const size_t bfBytes = nElems * 2;

  char* ws = (char*)d_ws;
  __bf16* qbf  = (__bf16*)(ws);
  __bf16* kbf  = (__bf16*)(ws + bfBytes);
  __bf16* vtbf = (__bf16*)(ws + 2 * bfBytes);
  float*  Opart = (float*)(ws + 3 * bfBytes);
  float2* mlp   = (float2*)(ws + 3 * bfBytes + (size_t)NSPLIT * nElems * 4);

  const size_t needSplit = 3 * bfBytes + (size_t)NSPLIT * nElems * 4 +
                           (size_t)NSPLIT * B * Nq * 8;
  const int NS = (ws_size >= needSplit) ? NSPLIT : 1;

  const float alpha = 1.4426950408889634f / sqrtf((float)D);  // log2(e)/sqrt(D)

  proj_all<<<dim3(B * Nq / 64, 3), 256, 0, stream>>>(
      Q, K, V, Wq, bq, Wk, bk, Wv, bv, qbf, kbf, vtbf, Nk, alpha);

  const int nx = Nq / 128;
  if (NS == 1) {
    attn_fwd<<<dim3(nx * B), 256, 0, stream>>>(
        qbf, kbf, vtbf, out, nullptr, Nq, Nk, 1, B);
  } else {
    attn_fwd<<<dim3(nx * NS * B), 256, 0, stream>>>(
        qbf, kbf, vtbf, Opart, mlp, Nq, Nk, NS, B);
    attn_combine<<<dim3(B * Nq / 2), 256, 0, stream>>>(
        Opart, mlp, out, NS, B * Nq);
  }
}